// Round 1
// baseline (19863.260 us; speedup 1.0000x reference)
//
#include <hip/hip_runtime.h>
#include <hip/hip_cooperative_groups.h>

namespace cg = cooperative_groups;

#define NB 32      // batch
#define NS 128     // src len
#define NT 128     // tgt len
#define NH 512     // hidden
#define NVS 8000   // src vocab
#define NVE 8000   // tgt vocab

__device__ __forceinline__ float sigm(float x) { return 1.0f / (1.0f + expf(-x)); }

// ---------------------------------------------------------------------------
// Cooperative scan: 128 encoder + 128 decoder LSTM steps.
// 256 blocks x 256 threads. Block g owns b-half (g&1: 16 batch rows) and
// m-slice (g>>1)*4 .. +4 (all 4 gates for those m) -> computes 16 rows x 16 b
// gate values per step and the cell update locally. h double-buffered in
// global ws; c persistent in LDS. One grid.sync per step.
// ---------------------------------------------------------------------------
__global__ __launch_bounds__(256) void scan_kernel(
    const int* __restrict__ in_tok, const int* __restrict__ out_tok,
    const float* __restrict__ We_ih, const float* __restrict__ We_hh,
    const float* __restrict__ be_ih, const float* __restrict__ be_hh,
    const float* __restrict__ Wd_ih, const float* __restrict__ Wd_hh,
    const float* __restrict__ bd_ih, const float* __restrict__ bd_hh,
    float* __restrict__ h_buf,      // [2][NB][NH]
    float* __restrict__ enc_out,    // [NS][NB][NH]
    float* __restrict__ dec_h)      // [NT][NB][NH]
{
  cg::grid_group grid = cg::this_grid();
  __shared__ float h_lds[16 * 516];   // 16 b-rows, padded stride 516
  __shared__ float gbuf[16][16];      // [r][bl]
  __shared__ float c_buf[4][16];      // [i][bl] persistent cell state

  const int tid = threadIdx.x;
  const int g   = blockIdx.x;
  const int bg  = g & 1;        // which 16-batch half
  const int mg  = g >> 1;       // m-group 0..127
  const int r   = tid >> 4;     // 0..15 : gate-row within block
  const int bl  = tid & 15;     // local batch
  const int b   = bg * 16 + bl;
  const int q   = r >> 2;       // gate index (i,f,g,o)
  const int i   = r & 3;        // m within slice
  const int m   = mg * 4 + i;
  const int j   = q * NH + m;   // row in [0,2048)

  const float bias_e = be_ih[j] + be_hh[j];
  const float bias_d = bd_ih[j] + bd_hh[j];
  const float* Wrow_e = We_hh + (size_t)j * NH;
  const float* Wrow_d = Wd_hh + (size_t)j * NH;
  const float* Wcol_e = We_ih + (size_t)j * NVS;
  const float* Wcol_d = Wd_ih + (size_t)j * NVE;

  if (tid < 64) c_buf[tid >> 4][tid & 15] = 0.0f;
  __syncthreads();

  for (int s = 0; s < NS + NT; ++s) {
    const bool enc = (s < NS);
    const int st  = enc ? s : s - NS;
    const int tok = enc ? in_tok[b * NS + st] : out_tok[b * NT + st];
    const float xp = enc ? Wcol_e[tok] : Wcol_d[tok];   // embedding gather (latency-hidden)
    const float bias = enc ? bias_e : bias_d;
    const float* __restrict__ Wrow = enc ? Wrow_e : Wrow_d;

    float acc = 0.0f;
    if (s > 0) {
      // stage 16 x 512 h-slice into LDS (coalesced float4)
      const float* hsrc = h_buf + ((s - 1) & 1) * (NB * NH) + bg * 16 * NH;
      for (int u = tid; u < 2048; u += 256) {
        const int bb = u >> 7;
        const int kk = (u & 127) << 2;
        const float4 v = *(const float4*)(hsrc + bb * NH + kk);
        *(float4*)&h_lds[bb * 516 + kk] = v;
      }
      __syncthreads();
      const float* hrow = &h_lds[bl * 516];
      #pragma unroll 8
      for (int k = 0; k < NH; k += 4) {
        const float4 hv = *(const float4*)(hrow + k);
        const float4 wv = *(const float4*)(Wrow + k);
        acc += hv.x * wv.x + hv.y * wv.y + hv.z * wv.z + hv.w * wv.w;
      }
    }
    gbuf[r][bl] = acc + xp + bias;
    __syncthreads();

    if (tid < 64) {  // cell update: 4 m x 16 b
      const int ii = tid >> 4;
      const int bb = tid & 15;
      const float gi = gbuf[ii][bb];
      const float gf = gbuf[4 + ii][bb];
      const float gg = gbuf[8 + ii][bb];
      const float go = gbuf[12 + ii][bb];
      const float co = c_buf[ii][bb];
      const float cn = sigm(gf) * co + sigm(gi) * tanhf(gg);
      const float hn = sigm(go) * tanhf(cn);
      c_buf[ii][bb] = cn;
      const int bglob = bg * 16 + bb;
      const int mm = mg * 4 + ii;
      h_buf[(s & 1) * (NB * NH) + bglob * NH + mm] = hn;
      float* dst = enc ? (enc_out + ((size_t)st * NB + bglob) * NH + mm)
                       : (dec_h  + ((size_t)st * NB + bglob) * NH + mm);
      *dst = hn;
    }
    __threadfence();
    grid.sync();
    __threadfence();
  }
}

// ---------------------------------------------------------------------------
// Generic 64x64-tile fp32 GEMM: C[m][n] = sum_k A[m][k]*B[n][k] (+bias,+act)
// TRANSB==0: B is [N][K] rows (weight matrices). TRANSB==1: B is [K][N].
// Optional concat-A (A2/ksplit), optional batched-z offsets, optional
// (t*B+b)->(b*T+t) output row swap (CSWAP) for writing logits to d_out.
// All shapes divide tiles exactly for this problem.
// ---------------------------------------------------------------------------
template<int TRANSB, int CSWAP, int ACT>
__global__ __launch_bounds__(256) void gemm64(
    const float* __restrict__ A, const float* __restrict__ Bm,
    float* __restrict__ C, const float* __restrict__ bias,
    const float* __restrict__ A2, int ksplit,
    int M, int N, int K, int lda, int ldb, int ldc,
    long batchA, long batchB, long batchC)
{
  __shared__ float As[16][68];
  __shared__ float Bs[16][68];
  const int z = blockIdx.z;
  A += (long)z * batchA;
  if (A2 != nullptr) A2 += (long)z * batchA;
  Bm += (long)z * batchB;
  C  += (long)z * batchC;
  const int m0 = blockIdx.y << 6;
  const int n0 = blockIdx.x << 6;
  const int tid = threadIdx.x;
  const int tx = tid & 15;
  const int ty = tid >> 4;
  float acc[4][4] = {};

  for (int k0 = 0; k0 < K; k0 += 16) {
    {
      const int mrow = tid >> 2;
      const int kc = (tid & 3) << 2;
      const float* base = A;
      int keff = k0;
      if (A2 != nullptr && k0 >= ksplit) { base = A2; keff = k0 - ksplit; }
      const float4 v = *(const float4*)(base + (long)(m0 + mrow) * lda + keff + kc);
      As[kc + 0][mrow] = v.x; As[kc + 1][mrow] = v.y;
      As[kc + 2][mrow] = v.z; As[kc + 3][mrow] = v.w;
    }
    if (TRANSB == 0) {
      const int nrow = tid >> 2;
      const int kc = (tid & 3) << 2;
      const float4 v = *(const float4*)(Bm + (long)(n0 + nrow) * ldb + k0 + kc);
      Bs[kc + 0][nrow] = v.x; Bs[kc + 1][nrow] = v.y;
      Bs[kc + 2][nrow] = v.z; Bs[kc + 3][nrow] = v.w;
    } else {
      const int krow = tid >> 4;
      const int nc = (tid & 15) << 2;
      const float4 v = *(const float4*)(Bm + (long)(k0 + krow) * ldb + n0 + nc);
      *(float4*)&Bs[krow][nc] = v;
    }
    __syncthreads();
    #pragma unroll
    for (int kk = 0; kk < 16; ++kk) {
      const float4 a4 = *(const float4*)&As[kk][ty << 2];
      const float4 b4 = *(const float4*)&Bs[kk][tx << 2];
      const float a[4]  = {a4.x, a4.y, a4.z, a4.w};
      const float bv[4] = {b4.x, b4.y, b4.z, b4.w};
      #pragma unroll
      for (int ii = 0; ii < 4; ++ii)
        #pragma unroll
        for (int jj = 0; jj < 4; ++jj)
          acc[ii][jj] = fmaf(a[ii], bv[jj], acc[ii][jj]);
    }
    __syncthreads();
  }

  const int n = n0 + (tx << 2);
  float4 bb4 = {0.f, 0.f, 0.f, 0.f};
  if (bias) { bb4.x = bias[n]; bb4.y = bias[n + 1]; bb4.z = bias[n + 2]; bb4.w = bias[n + 3]; }
  #pragma unroll
  for (int ii = 0; ii < 4; ++ii) {
    const int mrow = m0 + (ty << 2) + ii;
    float4 o;
    o.x = acc[ii][0] + bb4.x; o.y = acc[ii][1] + bb4.y;
    o.z = acc[ii][2] + bb4.z; o.w = acc[ii][3] + bb4.w;
    if (ACT == 1) { o.x = tanhf(o.x); o.y = tanhf(o.y); o.z = tanhf(o.z); o.w = tanhf(o.w); }
    long orow = mrow;
    if (CSWAP) orow = (long)(mrow & (NB - 1)) * NT + (mrow >> 5);  // (t*B+b) -> (b*T+t)
    *(float4*)(C + orow * (long)ldc + n) = o;
  }
}

// softmax over S=128 per (t,b) row, in place
__global__ __launch_bounds__(128) void softmax_s(float* __restrict__ sc) {
  const long row = blockIdx.x;
  float* p = sc + row * NS;
  const float x = p[threadIdx.x];
  float mx = x;
  for (int o = 32; o; o >>= 1) mx = fmaxf(mx, __shfl_xor(mx, o));
  __shared__ float r0[2], r1[2];
  const int w = threadIdx.x >> 6;
  if ((threadIdx.x & 63) == 0) r0[w] = mx;
  __syncthreads();
  mx = fmaxf(r0[0], r0[1]);
  const float e = expf(x - mx);
  float sum = e;
  for (int o = 32; o; o >>= 1) sum += __shfl_xor(sum, o);
  if ((threadIdx.x & 63) == 0) r1[w] = sum;
  __syncthreads();
  sum = r1[0] + r1[1];
  p[threadIdx.x] = e / sum;
}

// softmax over VE=8000 per (b,t) row of d_out, in place
__global__ __launch_bounds__(256) void softmax_v(float* __restrict__ out) {
  const long row = blockIdx.x;
  float* p = out + row * NVE;
  float v[32];
  float mx = -1e30f;
  #pragma unroll
  for (int it = 0; it < 32; ++it) {
    const int idx = (it << 8) + threadIdx.x;
    v[it] = (idx < NVE) ? p[idx] : -1e30f;
    mx = fmaxf(mx, v[it]);
  }
  for (int o = 32; o; o >>= 1) mx = fmaxf(mx, __shfl_xor(mx, o));
  __shared__ float red[4], red2[4];
  const int w = threadIdx.x >> 6;
  if ((threadIdx.x & 63) == 0) red[w] = mx;
  __syncthreads();
  mx = fmaxf(fmaxf(red[0], red[1]), fmaxf(red[2], red[3]));
  float sum = 0.0f;
  #pragma unroll
  for (int it = 0; it < 32; ++it) {
    const int idx = (it << 8) + threadIdx.x;
    if (idx < NVE) { v[it] = expf(v[it] - mx); sum += v[it]; }
  }
  for (int o = 32; o; o >>= 1) sum += __shfl_xor(sum, o);
  if ((threadIdx.x & 63) == 0) red2[w] = sum;
  __syncthreads();
  sum = red2[0] + red2[1] + red2[2] + red2[3];
  const float inv = 1.0f / sum;
  #pragma unroll
  for (int it = 0; it < 32; ++it) {
    const int idx = (it << 8) + threadIdx.x;
    if (idx < NVE) p[idx] = v[it] * inv;
  }
}

extern "C" void kernel_launch(void* const* d_in, const int* in_sizes, int n_in,
                              void* d_out, int out_size, void* d_ws, size_t ws_size,
                              hipStream_t stream) {
  const int*   in_tok = (const int*)d_in[0];
  const int*   out_tok = (const int*)d_in[1];
  const float* Wa    = (const float*)d_in[2];
  const float* ba    = (const float*)d_in[3];
  const float* W1    = (const float*)d_in[4];
  const float* b1    = (const float*)d_in[5];
  const float* W2    = (const float*)d_in[6];
  const float* b2    = (const float*)d_in[7];
  const float* We_ih = (const float*)d_in[8];
  const float* We_hh = (const float*)d_in[9];
  const float* be_ih = (const float*)d_in[10];
  const float* be_hh = (const float*)d_in[11];
  const float* Wd_ih = (const float*)d_in[12];
  const float* Wd_hh = (const float*)d_in[13];
  const float* bd_ih = (const float*)d_in[14];
  const float* bd_hh = (const float*)d_in[15];

  float* ws      = (float*)d_ws;
  float* h_buf   = ws;                 // 2*32*512          = 32768
  float* enc_out = ws + 32768;         // 128*32*512        = 2097152
  float* dec_h   = ws + 2129920;       // 128*32*512
  float* proj    = ws + 4227072;       // 128*32*512
  float* scores  = ws + 6324224;       // 128*32*128        = 524288
  float* ctx     = ws + 6848512;       // 128*32*512
  float* hid     = ws + 8945664;       // 128*32*512        (end: 11042816 floats = 44.2 MB)
  float* out     = (float*)d_out;

  // 1. encoder + decoder-LSTM scan (cooperative, 256 grid syncs)
  {
    void* args[13];
    args[0] = (void*)&in_tok; args[1] = (void*)&out_tok;
    args[2] = (void*)&We_ih;  args[3] = (void*)&We_hh;
    args[4] = (void*)&be_ih;  args[5] = (void*)&be_hh;
    args[6] = (void*)&Wd_ih;  args[7] = (void*)&Wd_hh;
    args[8] = (void*)&bd_ih;  args[9] = (void*)&bd_hh;
    args[10] = (void*)&h_buf; args[11] = (void*)&enc_out; args[12] = (void*)&dec_h;
    hipLaunchCooperativeKernel((void*)scan_kernel, dim3(256), dim3(256), args, 0, stream);
  }

  // 2. proj_enc = enc_out @ Wa^T + ba           [4096,512] K=512
  gemm64<0,0,0><<<dim3(8,64,1), 256, 0, stream>>>(
      enc_out, Wa, proj, ba, nullptr, 1 << 30,
      4096, 512, 512, 512, 512, 512, 0, 0, 0);

  // 3. scores[t,b,s] = dec_h . proj_enc (batched over b)   M=T,N=S,K=H
  gemm64<0,0,0><<<dim3(2,2,NB), 256, 0, stream>>>(
      dec_h, proj, scores, nullptr, nullptr, 1 << 30,
      NT, NS, NH, NB * NH, NB * NH, NB * NS,
      (long)NH, (long)NH, (long)NS);

  // 4. softmax over s
  softmax_s<<<dim3(NT * NB), 128, 0, stream>>>(scores);

  // 5. context[t,b,h] = w @ enc_out (batched over b, B is [K][N])  M=T,N=H,K=S
  gemm64<1,0,0><<<dim3(8,2,NB), 256, 0, stream>>>(
      scores, enc_out, ctx, nullptr, nullptr, 1 << 30,
      NT, NH, NS, NB * NS, NB * NH, NB * NH,
      (long)NS, (long)NH, (long)NH);

  // 6. hid = tanh(concat(dec_h, ctx) @ W1^T + b1)   [4096,512] K=1024
  gemm64<0,0,1><<<dim3(8,64,1), 256, 0, stream>>>(
      dec_h, W1, hid, b1, ctx, 512,
      4096, 512, 1024, 512, 1024, 512, 0, 0, 0);

  // 7. logits = hid @ W2^T + b2 -> d_out[b][t][v]   [4096,8000] K=512
  gemm64<0,1,0><<<dim3(125,64,1), 256, 0, stream>>>(
      hid, W2, out, b2, nullptr, 1 << 30,
      4096, NVE, 512, 512, 512, NVE, 0, 0, 0);

  // 8. softmax over vocab, in place on d_out
  softmax_v<<<dim3(NB * NT), 256, 0, stream>>>(out);
}

// Round 3
// 2699.382 us; speedup vs baseline: 7.3584x; 7.3584x over previous
//
#include <hip/hip_runtime.h>
#include <hip/hip_cooperative_groups.h>

#define NB 32      // batch
#define NS 128     // src len
#define NT 128     // tgt len
#define NH 512     // hidden
#define NVS 8000   // src vocab
#define NVE 8000   // tgt vocab

typedef float fx4 __attribute__((ext_vector_type(4)));

__device__ __forceinline__ float sigm(float x) { return 1.0f / (1.0f + expf(-x)); }

// Coherent (L1/L2-bypassing, Infinity-Cache-served) 16B load/store for
// cross-XCD h exchange. Consumers must s_waitcnt vmcnt(0) + sched_barrier(0)
// before using loaded values.
__device__ __forceinline__ fx4 load_cg(const float* p) {
  fx4 v;
  asm volatile("global_load_dwordx4 %0, %1, off sc0 sc1" : "=v"(v) : "v"(p));
  return v;
}
__device__ __forceinline__ void store_cg(float* p, fx4 v) {
  asm volatile("global_store_dwordx4 %0, %1, off sc0 sc1" :: "v"(p), "v"(v) : "memory");
}

// ---------------------------------------------------------------------------
// Scan: 128 encoder + 128 decoder LSTM steps. 256 blocks x 256 threads,
// cooperative launch ONLY for guaranteed co-residency — no grid.sync().
// Block g: bg = g&1 (16-batch half), mg = g>>1 (4 m-rows, all 4 gates).
// Cross-block exchange: h (64KB/step) via sc0sc1 stores/loads through L3;
// point-to-point flag sync (producer flag = step+1 after h write).
// W_hh rows stay L1-resident — no cache invalidation anywhere.
// ---------------------------------------------------------------------------
__global__ __launch_bounds__(256) void scan_kernel(
    const int* __restrict__ in_tok, const int* __restrict__ out_tok,
    const float* __restrict__ We_ih, const float* __restrict__ We_hh,
    const float* __restrict__ be_ih, const float* __restrict__ be_hh,
    const float* __restrict__ Wd_ih, const float* __restrict__ Wd_hh,
    const float* __restrict__ bd_ih, const float* __restrict__ bd_hh,
    float* __restrict__ h_buf,      // [2][NB][NH]
    float* __restrict__ enc_out,    // [NS][NB][NH]
    float* __restrict__ dec_h,      // [NT][NB][NH]
    int* __restrict__ flags)        // [256], memset to 0 before launch
{
  __shared__ float h_lds[16 * 516];   // 16 b-rows, padded stride 516
  __shared__ float gbuf[16][16];      // [r][bl]
  __shared__ float c_buf[4][16];      // [m][bl] persistent cell state
  __shared__ float hstage[16][4];     // [bl][m] new h staging for packed store

  const int tid = threadIdx.x;
  const int g   = blockIdx.x;
  const int bg  = g & 1;        // which 16-batch half
  const int mg  = g >> 1;       // m-group 0..127
  const int r   = tid >> 4;     // 0..15 : gate-row within block
  const int bl  = tid & 15;     // local batch
  const int b   = bg * 16 + bl;
  const int q   = r >> 2;       // gate index (i,f,g,o)
  const int i   = r & 3;        // m within slice
  const int m   = mg * 4 + i;
  const int j   = q * NH + m;   // row in [0,2048)

  const float bias_e = be_ih[j] + be_hh[j];
  const float bias_d = bd_ih[j] + bd_hh[j];
  const float* Wrow_e = We_hh + (size_t)j * NH;
  const float* Wrow_d = Wd_hh + (size_t)j * NH;
  const float* Wcol_e = We_ih + (size_t)j * NVS;
  const float* Wcol_d = Wd_ih + (size_t)j * NVE;

  if (tid < 64) c_buf[tid >> 4][tid & 15] = 0.0f;
  __syncthreads();

  for (int s = 0; s < NS + NT; ++s) {
    const bool enc = (s < NS);
    const int st  = enc ? s : s - NS;
    const int tok = enc ? in_tok[b * NS + st] : out_tok[b * NT + st];
    const float xp = enc ? Wcol_e[tok] : Wcol_d[tok];   // embedding gather (latency-hidden)
    const float bias = enc ? bias_e : bias_d;
    const float* __restrict__ Wrow = enc ? Wrow_e : Wrow_d;

    float acc = 0.0f;
    if (s > 0) {
      // wait for all 128 same-half producers to have published h^{s-1}
      if (tid < 128) {
        const int idx = (tid << 1) | bg;
        while (__hip_atomic_load(&flags[idx], __ATOMIC_RELAXED,
                                 __HIP_MEMORY_SCOPE_AGENT) < s)
          __builtin_amdgcn_s_sleep(1);
      }
      __syncthreads();
      // stage 16 x 512 h-slice into LDS via coherent dwordx4 loads
      const float* hsrc = h_buf + ((s - 1) & 1) * (NB * NH) + bg * 16 * NH;
      fx4 tmp[8];
      #pragma unroll
      for (int it = 0; it < 8; ++it)
        tmp[it] = load_cg(hsrc + ((tid + (it << 8)) << 2));
      asm volatile("s_waitcnt vmcnt(0)" ::: "memory");
      __builtin_amdgcn_sched_barrier(0);
      #pragma unroll
      for (int it = 0; it < 8; ++it) {
        const int u = tid + (it << 8);
        const int bb = u >> 7;          // 128 float4 per 512-float row
        const int k4 = u & 127;
        *(fx4*)&h_lds[bb * 516 + (k4 << 2)] = tmp[it];
      }
      __syncthreads();
      const float* hrow = &h_lds[bl * 516];
      #pragma unroll 8
      for (int k = 0; k < NH; k += 4) {
        const float4 hv = *(const float4*)(hrow + k);
        const float4 wv = *(const float4*)(Wrow + k);
        acc += hv.x * wv.x + hv.y * wv.y + hv.z * wv.z + hv.w * wv.w;
      }
    }
    gbuf[r][bl] = acc + xp + bias;
    __syncthreads();

    if (tid < 64) {  // cell update: 4 m x 16 b
      const int ii = tid >> 4;
      const int bb = tid & 15;
      const float gi = gbuf[ii][bb];
      const float gf = gbuf[4 + ii][bb];
      const float gg = gbuf[8 + ii][bb];
      const float go = gbuf[12 + ii][bb];
      const float co = c_buf[ii][bb];
      const float cn = sigm(gf) * co + sigm(gi) * tanhf(gg);
      const float hn = sigm(go) * tanhf(cn);
      c_buf[ii][bb] = cn;
      hstage[bb][ii] = hn;
    }
    __syncthreads();
    if (tid < 16) {  // packed 16B coherent store of this block's h chunk
      const fx4 hv = *(const fx4*)&hstage[tid][0];
      const int bglob = bg * 16 + tid;
      store_cg(h_buf + (s & 1) * (NB * NH) + bglob * NH + mg * 4, hv);
      float* dst = enc ? (enc_out + ((size_t)st * NB + bglob) * NH + mg * 4)
                       : (dec_h  + ((size_t)st * NB + bglob) * NH + mg * 4);
      *(fx4*)dst = hv;   // plain store; visible at kernel end
    }
    asm volatile("s_waitcnt vmcnt(0)" ::: "memory");  // drain h stores (wave 0)
    __syncthreads();
    if (tid == 0)
      __hip_atomic_store(&flags[g], s + 1, __ATOMIC_RELAXED,
                         __HIP_MEMORY_SCOPE_AGENT);
    // no barrier needed here: next-step spin provides the ordering
  }
}

// ---------------------------------------------------------------------------
// Generic 64x64-tile fp32 GEMM: C[m][n] = sum_k A[m][k]*B[n][k] (+bias,+act)
// TRANSB==0: B is [N][K] rows. TRANSB==1: B is [K][N]. Optional concat-A
// (A2/ksplit), batched-z offsets, (t*B+b)->(b*T+t) output row swap (CSWAP).
// ---------------------------------------------------------------------------
template<int TRANSB, int CSWAP, int ACT>
__global__ __launch_bounds__(256) void gemm64(
    const float* __restrict__ A, const float* __restrict__ Bm,
    float* __restrict__ C, const float* __restrict__ bias,
    const float* __restrict__ A2, int ksplit,
    int M, int N, int K, int lda, int ldb, int ldc,
    long batchA, long batchB, long batchC)
{
  __shared__ float As[16][68];
  __shared__ float Bs[16][68];
  const int z = blockIdx.z;
  A += (long)z * batchA;
  if (A2 != nullptr) A2 += (long)z * batchA;
  Bm += (long)z * batchB;
  C  += (long)z * batchC;
  const int m0 = blockIdx.y << 6;
  const int n0 = blockIdx.x << 6;
  const int tid = threadIdx.x;
  const int tx = tid & 15;
  const int ty = tid >> 4;
  float acc[4][4] = {};

  for (int k0 = 0; k0 < K; k0 += 16) {
    {
      const int mrow = tid >> 2;
      const int kc = (tid & 3) << 2;
      const float* base = A;
      int keff = k0;
      if (A2 != nullptr && k0 >= ksplit) { base = A2; keff = k0 - ksplit; }
      const float4 v = *(const float4*)(base + (long)(m0 + mrow) * lda + keff + kc);
      As[kc + 0][mrow] = v.x; As[kc + 1][mrow] = v.y;
      As[kc + 2][mrow] = v.z; As[kc + 3][mrow] = v.w;
    }
    if (TRANSB == 0) {
      const int nrow = tid >> 2;
      const int kc = (tid & 3) << 2;
      const float4 v = *(const float4*)(Bm + (long)(n0 + nrow) * ldb + k0 + kc);
      Bs[kc + 0][nrow] = v.x; Bs[kc + 1][nrow] = v.y;
      Bs[kc + 2][nrow] = v.z; Bs[kc + 3][nrow] = v.w;
    } else {
      const int krow = tid >> 4;
      const int nc = (tid & 15) << 2;
      const float4 v = *(const float4*)(Bm + (long)(k0 + krow) * ldb + n0 + nc);
      *(float4*)&Bs[krow][nc] = v;
    }
    __syncthreads();
    #pragma unroll
    for (int kk = 0; kk < 16; ++kk) {
      const float4 a4 = *(const float4*)&As[kk][ty << 2];
      const float4 b4 = *(const float4*)&Bs[kk][tx << 2];
      const float a[4]  = {a4.x, a4.y, a4.z, a4.w};
      const float bv[4] = {b4.x, b4.y, b4.z, b4.w};
      #pragma unroll
      for (int ii = 0; ii < 4; ++ii)
        #pragma unroll
        for (int jj = 0; jj < 4; ++jj)
          acc[ii][jj] = fmaf(a[ii], bv[jj], acc[ii][jj]);
    }
    __syncthreads();
  }

  const int n = n0 + (tx << 2);
  float4 bb4 = {0.f, 0.f, 0.f, 0.f};
  if (bias) { bb4.x = bias[n]; bb4.y = bias[n + 1]; bb4.z = bias[n + 2]; bb4.w = bias[n + 3]; }
  #pragma unroll
  for (int ii = 0; ii < 4; ++ii) {
    const int mrow = m0 + (ty << 2) + ii;
    float4 o;
    o.x = acc[ii][0] + bb4.x; o.y = acc[ii][1] + bb4.y;
    o.z = acc[ii][2] + bb4.z; o.w = acc[ii][3] + bb4.w;
    if (ACT == 1) { o.x = tanhf(o.x); o.y = tanhf(o.y); o.z = tanhf(o.z); o.w = tanhf(o.w); }
    long orow = mrow;
    if (CSWAP) orow = (long)(mrow & (NB - 1)) * NT + (mrow >> 5);  // (t*B+b) -> (b*T+t)
    *(float4*)(C + orow * (long)ldc + n) = o;
  }
}

// softmax over S=128 per (t,b) row, in place
__global__ __launch_bounds__(128) void softmax_s(float* __restrict__ sc) {
  const long row = blockIdx.x;
  float* p = sc + row * NS;
  const float x = p[threadIdx.x];
  float mx = x;
  for (int o = 32; o; o >>= 1) mx = fmaxf(mx, __shfl_xor(mx, o));
  __shared__ float r0[2], r1[2];
  const int w = threadIdx.x >> 6;
  if ((threadIdx.x & 63) == 0) r0[w] = mx;
  __syncthreads();
  mx = fmaxf(r0[0], r0[1]);
  const float e = expf(x - mx);
  float sum = e;
  for (int o = 32; o; o >>= 1) sum += __shfl_xor(sum, o);
  if ((threadIdx.x & 63) == 0) r1[w] = sum;
  __syncthreads();
  sum = r1[0] + r1[1];
  p[threadIdx.x] = e / sum;
}

// softmax over VE=8000 per (b,t) row of d_out, in place
__global__ __launch_bounds__(256) void softmax_v(float* __restrict__ out) {
  const long row = blockIdx.x;
  float* p = out + row * NVE;
  float v[32];
  float mx = -1e30f;
  #pragma unroll
  for (int it = 0; it < 32; ++it) {
    const int idx = (it << 8) + threadIdx.x;
    v[it] = (idx < NVE) ? p[idx] : -1e30f;
    mx = fmaxf(mx, v[it]);
  }
  for (int o = 32; o; o >>= 1) mx = fmaxf(mx, __shfl_xor(mx, o));
  __shared__ float red[4], red2[4];
  const int w = threadIdx.x >> 6;
  if ((threadIdx.x & 63) == 0) red[w] = mx;
  __syncthreads();
  mx = fmaxf(fmaxf(red[0], red[1]), fmaxf(red[2], red[3]));
  float sum = 0.0f;
  #pragma unroll
  for (int it = 0; it < 32; ++it) {
    const int idx = (it << 8) + threadIdx.x;
    if (idx < NVE) { v[it] = expf(v[it] - mx); sum += v[it]; }
  }
  for (int o = 32; o; o >>= 1) sum += __shfl_xor(sum, o);
  if ((threadIdx.x & 63) == 0) red2[w] = sum;
  __syncthreads();
  sum = red2[0] + red2[1] + red2[2] + red2[3];
  const float inv = 1.0f / sum;
  #pragma unroll
  for (int it = 0; it < 32; ++it) {
    const int idx = (it << 8) + threadIdx.x;
    if (idx < NVE) p[idx] = v[it] * inv;
  }
}

extern "C" void kernel_launch(void* const* d_in, const int* in_sizes, int n_in,
                              void* d_out, int out_size, void* d_ws, size_t ws_size,
                              hipStream_t stream) {
  const int*   in_tok = (const int*)d_in[0];
  const int*   out_tok = (const int*)d_in[1];
  const float* Wa    = (const float*)d_in[2];
  const float* ba    = (const float*)d_in[3];
  const float* W1    = (const float*)d_in[4];
  const float* b1    = (const float*)d_in[5];
  const float* W2    = (const float*)d_in[6];
  const float* b2    = (const float*)d_in[7];
  const float* We_ih = (const float*)d_in[8];
  const float* We_hh = (const float*)d_in[9];
  const float* be_ih = (const float*)d_in[10];
  const float* be_hh = (const float*)d_in[11];
  const float* Wd_ih = (const float*)d_in[12];
  const float* Wd_hh = (const float*)d_in[13];
  const float* bd_ih = (const float*)d_in[14];
  const float* bd_hh = (const float*)d_in[15];

  float* ws      = (float*)d_ws;
  float* h_buf   = ws;                 // 2*32*512          = 32768
  float* enc_out = ws + 32768;         // 128*32*512        = 2097152
  float* dec_h   = ws + 2129920;       // 128*32*512
  float* proj    = ws + 4227072;       // 128*32*512
  float* scores  = ws + 6324224;       // 128*32*128        = 524288
  float* ctx     = ws + 6848512;       // 128*32*512
  float* hid     = ws + 8945664;       // 128*32*512
  int*   flags   = (int*)(ws + 11042816);  // 256 ints
  float* out     = (float*)d_out;

  (void)hipMemsetAsync((void*)flags, 0, 256 * sizeof(int), stream);

  // 1. encoder + decoder-LSTM scan (co-resident, p2p flag sync)
  {
    void* args[14];
    args[0] = (void*)&in_tok; args[1] = (void*)&out_tok;
    args[2] = (void*)&We_ih;  args[3] = (void*)&We_hh;
    args[4] = (void*)&be_ih;  args[5] = (void*)&be_hh;
    args[6] = (void*)&Wd_ih;  args[7] = (void*)&Wd_hh;
    args[8] = (void*)&bd_ih;  args[9] = (void*)&bd_hh;
    args[10] = (void*)&h_buf; args[11] = (void*)&enc_out; args[12] = (void*)&dec_h;
    args[13] = (void*)&flags;
    (void)hipLaunchCooperativeKernel((void*)scan_kernel, dim3(256), dim3(256), args, 0, stream);
  }

  // 2. proj_enc = enc_out @ Wa^T + ba           [4096,512] K=512
  gemm64<0,0,0><<<dim3(8,64,1), 256, 0, stream>>>(
      enc_out, Wa, proj, ba, nullptr, 1 << 30,
      4096, 512, 512, 512, 512, 512, 0, 0, 0);

  // 3. scores[t,b,s] = dec_h . proj_enc (batched over b)   M=T,N=S,K=H
  gemm64<0,0,0><<<dim3(2,2,NB), 256, 0, stream>>>(
      dec_h, proj, scores, nullptr, nullptr, 1 << 30,
      NT, NS, NH, NB * NH, NB * NH, NB * NS,
      (long)NH, (long)NH, (long)NS);

  // 4. softmax over s
  softmax_s<<<dim3(NT * NB), 128, 0, stream>>>(scores);

  // 5. context[t,b,h] = w @ enc_out (batched over b, B is [K][N])  M=T,N=H,K=S
  gemm64<1,0,0><<<dim3(8,2,NB), 256, 0, stream>>>(
      scores, enc_out, ctx, nullptr, nullptr, 1 << 30,
      NT, NH, NS, NB * NS, NB * NH, NB * NH,
      (long)NS, (long)NH, (long)NH);

  // 6. hid = tanh(concat(dec_h, ctx) @ W1^T + b1)   [4096,512] K=1024
  gemm64<0,0,1><<<dim3(8,64,1), 256, 0, stream>>>(
      dec_h, W1, hid, b1, ctx, 512,
      4096, 512, 1024, 512, 1024, 512, 0, 0, 0);

  // 7. logits = hid @ W2^T + b2 -> d_out[b][t][v]   [4096,8000] K=512
  gemm64<0,1,0><<<dim3(125,64,1), 256, 0, stream>>>(
      hid, W2, out, b2, nullptr, 1 << 30,
      4096, NVE, 512, 512, 512, NVE, 0, 0, 0);

  // 8. softmax over vocab, in place on d_out
  softmax_v<<<dim3(NB * NT), 256, 0, stream>>>(out);
}

// Round 5
// 2239.869 us; speedup vs baseline: 8.8680x; 1.2052x over previous
//
#include <hip/hip_runtime.h>
#include <hip/hip_cooperative_groups.h>

#define NB 32      // batch
#define NS 128     // src len
#define NT 128     // tgt len
#define NH 512     // hidden
#define NVS 8000   // src vocab
#define NVE 8000   // tgt vocab

typedef float fx4 __attribute__((ext_vector_type(4)));

__device__ __forceinline__ float sigm(float x) { return 1.0f / (1.0f + expf(-x)); }

// Coherent (L1/L2-bypassing, Infinity-Cache-served) 16B load/store for
// cross-XCD h exchange.
__device__ __forceinline__ fx4 load_cg(const float* p) {
  fx4 v;
  asm volatile("global_load_dwordx4 %0, %1, off sc0 sc1" : "=v"(v) : "v"(p));
  return v;
}
__device__ __forceinline__ void store_cg(float* p, fx4 v) {
  asm volatile("global_store_dwordx4 %0, %1, off sc0 sc1" :: "v"(p), "v"(v) : "memory");
}

// ---------------------------------------------------------------------------
// Scan: 128 encoder + 128 decoder LSTM steps. 256 blocks x 256 threads,
// cooperative launch only for co-residency; p2p flag sync (R3 scheme).
// Block g: bg=g&1 (16-batch half), mg=g>>1 (4 m x 4 gates = 16 rows).
// Thread (r=tid>>4, bl=tid&15): serial 512-dot for gate row r, batch bl —
// EXACT R3 summation order (accuracy-verified). W slice staged in LDS once
// per phase (32KB, restaged at s=NS) -> no per-step global W traffic.
// ---------------------------------------------------------------------------
__global__ __launch_bounds__(256) void scan_kernel(
    const int* __restrict__ in_tok, const int* __restrict__ out_tok,
    const float* __restrict__ We_ih, const float* __restrict__ We_hh,
    const float* __restrict__ be_ih, const float* __restrict__ be_hh,
    const float* __restrict__ Wd_ih, const float* __restrict__ Wd_hh,
    const float* __restrict__ bd_ih, const float* __restrict__ bd_hh,
    float* __restrict__ h_buf,      // [2][NB][NH]
    float* __restrict__ enc_out,    // [NS][NB][NH]
    float* __restrict__ dec_h,      // [NT][NB][NH]
    int* __restrict__ flags)        // [256], memset 0 before launch
{
  __shared__ float W_lds[16][520];    // 16 gate rows x 512, padded
  __shared__ float h_lds[16 * 516];   // 16 b-rows, padded stride 516
  __shared__ float gbuf[16][16];      // [r][bl]
  __shared__ float c_buf[4][16];      // [m][bl] persistent cell state
  __shared__ float hstage[16][4];     // [bl][m]

  const int tid = threadIdx.x;
  const int g   = blockIdx.x;
  const int bg  = g & 1;        // which 16-batch half
  const int mg  = g >> 1;       // m-group 0..127
  const int r   = tid >> 4;     // gate-row 0..15
  const int bl  = tid & 15;     // local batch
  const int b   = bg * 16 + bl;
  const int q   = r >> 2;       // gate index (i,f,g,o)
  const int i   = r & 3;        // m within slice
  const int j   = q * NH + mg * 4 + i;  // global gate row

  const float bias_e = be_ih[j] + be_hh[j];
  const float bias_d = bd_ih[j] + bd_hh[j];
  const float* Wcol_e = We_ih + (size_t)j * NVS;
  const float* Wcol_d = Wd_ih + (size_t)j * NVE;

  if (tid < 64) c_buf[tid >> 4][tid & 15] = 0.0f;

  // stage encoder W_hh slice: 16 rows x 512 floats (coalesced float4)
  {
    const float* Wg = We_hh;
    for (int u = tid; u < 2048; u += 256) {
      const int rr = u >> 7;               // 128 float4 per row
      const int k4 = (u & 127) << 2;
      const int jj = (rr >> 2) * NH + mg * 4 + (rr & 3);
      *(float4*)&W_lds[rr][k4] = *(const float4*)(Wg + (size_t)jj * NH + k4);
    }
  }
  __syncthreads();

  for (int s = 0; s < NS + NT; ++s) {
    const bool enc = (s < NS);
    if (s == NS) {  // restage decoder W_hh (all prior W reads done: gbuf
                    // barrier of s=NS-1 already passed)
      const float* Wg = Wd_hh;
      for (int u = tid; u < 2048; u += 256) {
        const int rr = u >> 7;
        const int k4 = (u & 127) << 2;
        const int jj = (rr >> 2) * NH + mg * 4 + (rr & 3);
        *(float4*)&W_lds[rr][k4] = *(const float4*)(Wg + (size_t)jj * NH + k4);
      }
      __syncthreads();
    }
    const int st  = enc ? s : s - NS;
    const int tok = enc ? in_tok[b * NS + st] : out_tok[b * NT + st];
    const float xp = enc ? Wcol_e[tok] : Wcol_d[tok];   // HBM gather, hidden
    const float bias = enc ? bias_e : bias_d;
    const float* Wrow = &W_lds[r][0];

    float acc = 0.0f;
    if (s > 0) {
      // wait for all 128 same-half producers of h^{s-1}
      if (tid < 128) {
        const int idx = (tid << 1) | bg;
        while (__hip_atomic_load(&flags[idx], __ATOMIC_RELAXED,
                                 __HIP_MEMORY_SCOPE_AGENT) < s)
          __builtin_amdgcn_s_sleep(1);
      }
      __syncthreads();
      // stage 16 x 512 h-slice into LDS via coherent dwordx4 loads
      const float* hsrc = h_buf + ((s - 1) & 1) * (NB * NH) + bg * 16 * NH;
      fx4 tmp[8];
      #pragma unroll
      for (int it = 0; it < 8; ++it)
        tmp[it] = load_cg(hsrc + ((tid + (it << 8)) << 2));
      asm volatile("s_waitcnt vmcnt(0)" ::: "memory");
      __builtin_amdgcn_sched_barrier(0);
      #pragma unroll
      for (int it = 0; it < 8; ++it) {
        const int u = tid + (it << 8);
        const int bb = u >> 7;
        const int kk = (u & 127) << 2;
        *(fx4*)&h_lds[bb * 516 + kk] = tmp[it];
      }
      __syncthreads();
      // EXACT R3 inner loop (summation order preserved)
      const float* hrow = &h_lds[bl * 516];
      #pragma unroll 8
      for (int k = 0; k < NH; k += 4) {
        const float4 hv = *(const float4*)(hrow + k);
        const float4 wv = *(const float4*)(Wrow + k);
        acc += hv.x * wv.x + hv.y * wv.y + hv.z * wv.z + hv.w * wv.w;
      }
    }
    gbuf[r][bl] = acc + xp + bias;
    __syncthreads();

    if (tid < 64) {  // cell update: 4 m x 16 b
      const int ii = tid >> 4;
      const int bb = tid & 15;
      const float gi = gbuf[ii][bb];
      const float gf = gbuf[4 + ii][bb];
      const float gg = gbuf[8 + ii][bb];
      const float go = gbuf[12 + ii][bb];
      const float co = c_buf[ii][bb];
      const float cn = sigm(gf) * co + sigm(gi) * tanhf(gg);
      const float hn = sigm(go) * tanhf(cn);
      c_buf[ii][bb] = cn;
      hstage[bb][ii] = hn;
    }
    __syncthreads();
    if (tid < 16) {  // packed 16B coherent store of this block's h chunk
      const fx4 hv = *(const fx4*)&hstage[tid][0];
      const int bglob = bg * 16 + tid;
      store_cg(h_buf + (s & 1) * (NB * NH) + bglob * NH + mg * 4, hv);
      float* dst = enc ? (enc_out + ((size_t)st * NB + bglob) * NH + mg * 4)
                       : (dec_h  + ((size_t)st * NB + bglob) * NH + mg * 4);
      *(fx4*)dst = hv;
    }
    asm volatile("s_waitcnt vmcnt(0)" ::: "memory");  // wave 0 drains h stores
    __syncthreads();
    if (tid == 0)
      __hip_atomic_store(&flags[g], s + 1, __ATOMIC_RELAXED,
                         __HIP_MEMORY_SCOPE_AGENT);
  }
}

// ---------------------------------------------------------------------------
// 64x64-tile fp32 GEMM (small batched attention GEMMs).
// ---------------------------------------------------------------------------
template<int TRANSB, int CSWAP, int ACT>
__global__ __launch_bounds__(256) void gemm64(
    const float* __restrict__ A, const float* __restrict__ Bm,
    float* __restrict__ C, const float* __restrict__ bias,
    const float* __restrict__ A2, int ksplit,
    int M, int N, int K, int lda, int ldb, int ldc,
    long batchA, long batchB, long batchC)
{
  __shared__ float As[16][68];
  __shared__ float Bs[16][68];
  const int z = blockIdx.z;
  A += (long)z * batchA;
  if (A2 != nullptr) A2 += (long)z * batchA;
  Bm += (long)z * batchB;
  C  += (long)z * batchC;
  const int m0 = blockIdx.y << 6;
  const int n0 = blockIdx.x << 6;
  const int tid = threadIdx.x;
  const int tx = tid & 15;
  const int ty = tid >> 4;
  float acc[4][4] = {};

  for (int k0 = 0; k0 < K; k0 += 16) {
    {
      const int mrow = tid >> 2;
      const int kcq = (tid & 3) << 2;
      const float* base = A;
      int keff = k0;
      if (A2 != nullptr && k0 >= ksplit) { base = A2; keff = k0 - ksplit; }
      const float4 v = *(const float4*)(base + (long)(m0 + mrow) * lda + keff + kcq);
      As[kcq + 0][mrow] = v.x; As[kcq + 1][mrow] = v.y;
      As[kcq + 2][mrow] = v.z; As[kcq + 3][mrow] = v.w;
    }
    if (TRANSB == 0) {
      const int nrow = tid >> 2;
      const int kcq = (tid & 3) << 2;
      const float4 v = *(const float4*)(Bm + (long)(n0 + nrow) * ldb + k0 + kcq);
      Bs[kcq + 0][nrow] = v.x; Bs[kcq + 1][nrow] = v.y;
      Bs[kcq + 2][nrow] = v.z; Bs[kcq + 3][nrow] = v.w;
    } else {
      const int krow = tid >> 4;
      const int nc = (tid & 15) << 2;
      const float4 v = *(const float4*)(Bm + (long)(k0 + krow) * ldb + n0 + nc);
      *(float4*)&Bs[krow][nc] = v;
    }
    __syncthreads();
    #pragma unroll
    for (int kk = 0; kk < 16; ++kk) {
      const float4 a4 = *(const float4*)&As[kk][ty << 2];
      const float4 b4 = *(const float4*)&Bs[kk][tx << 2];
      const float a[4]  = {a4.x, a4.y, a4.z, a4.w};
      const float bv[4] = {b4.x, b4.y, b4.z, b4.w};
      #pragma unroll
      for (int ii = 0; ii < 4; ++ii)
        #pragma unroll
        for (int jj = 0; jj < 4; ++jj)
          acc[ii][jj] = fmaf(a[ii], bv[jj], acc[ii][jj]);
    }
    __syncthreads();
  }

  const int n = n0 + (tx << 2);
  float4 bb4 = {0.f, 0.f, 0.f, 0.f};
  if (bias) { bb4.x = bias[n]; bb4.y = bias[n + 1]; bb4.z = bias[n + 2]; bb4.w = bias[n + 3]; }
  #pragma unroll
  for (int ii = 0; ii < 4; ++ii) {
    const int mrow = m0 + (ty << 2) + ii;
    float4 o;
    o.x = acc[ii][0] + bb4.x; o.y = acc[ii][1] + bb4.y;
    o.z = acc[ii][2] + bb4.z; o.w = acc[ii][3] + bb4.w;
    if (ACT == 1) { o.x = tanhf(o.x); o.y = tanhf(o.y); o.z = tanhf(o.z); o.w = tanhf(o.w); }
    long orow = mrow;
    if (CSWAP) orow = (long)(mrow & (NB - 1)) * NT + (mrow >> 5);
    *(float4*)(C + orow * (long)ldc + n) = o;
  }
}

// ---------------------------------------------------------------------------
// 128x64-tile fp32 GEMM, 8x4 acc/thread (big weight GEMMs).
// ---------------------------------------------------------------------------
template<int CSWAP, int ACT>
__global__ __launch_bounds__(256) void gemm128(
    const float* __restrict__ A, const float* __restrict__ Bm,
    float* __restrict__ C, const float* __restrict__ bias,
    const float* __restrict__ A2, int ksplit,
    int M, int N, int K, int lda, int ldb, int ldc)
{
  __shared__ float As[16][132];
  __shared__ float Bs[16][68];
  const int m0 = blockIdx.y << 7;
  const int n0 = blockIdx.x << 6;
  const int tid = threadIdx.x;
  const int tx = tid & 15;
  const int ty = tid >> 4;
  float acc[8][4] = {};

  for (int k0 = 0; k0 < K; k0 += 16) {
    {
      const int mrow = tid >> 1;
      const int kq = (tid & 1) << 3;
      const float* base = A;
      int keff = k0;
      if (A2 != nullptr && k0 >= ksplit) { base = A2; keff = k0 - ksplit; }
      const float* p = base + (long)(m0 + mrow) * lda + keff + kq;
      const float4 v0 = *(const float4*)(p);
      const float4 v1 = *(const float4*)(p + 4);
      As[kq + 0][mrow] = v0.x; As[kq + 1][mrow] = v0.y;
      As[kq + 2][mrow] = v0.z; As[kq + 3][mrow] = v0.w;
      As[kq + 4][mrow] = v1.x; As[kq + 5][mrow] = v1.y;
      As[kq + 6][mrow] = v1.z; As[kq + 7][mrow] = v1.w;
    }
    {
      const int nrow = tid >> 2;
      const int kq = (tid & 3) << 2;
      const float4 v = *(const float4*)(Bm + (long)(n0 + nrow) * ldb + k0 + kq);
      Bs[kq + 0][nrow] = v.x; Bs[kq + 1][nrow] = v.y;
      Bs[kq + 2][nrow] = v.z; Bs[kq + 3][nrow] = v.w;
    }
    __syncthreads();
    #pragma unroll
    for (int kk = 0; kk < 16; ++kk) {
      const fx4 b4 = *(const fx4*)&Bs[kk][tx << 2];
      const fx4 a0 = *(const fx4*)&As[kk][ty << 3];
      const fx4 a1 = *(const fx4*)&As[kk][(ty << 3) + 4];
      #pragma unroll
      for (int ii = 0; ii < 4; ++ii) {
        #pragma unroll
        for (int jj = 0; jj < 4; ++jj) {
          acc[ii][jj]     = fmaf(a0[ii], b4[jj], acc[ii][jj]);
          acc[ii + 4][jj] = fmaf(a1[ii], b4[jj], acc[ii + 4][jj]);
        }
      }
    }
    __syncthreads();
  }

  const int n = n0 + (tx << 2);
  float4 bb4 = {0.f, 0.f, 0.f, 0.f};
  if (bias) { bb4.x = bias[n]; bb4.y = bias[n + 1]; bb4.z = bias[n + 2]; bb4.w = bias[n + 3]; }
  #pragma unroll
  for (int ii = 0; ii < 8; ++ii) {
    const int mrow = m0 + (ty << 3) + ii;
    float4 o;
    o.x = acc[ii][0] + bb4.x; o.y = acc[ii][1] + bb4.y;
    o.z = acc[ii][2] + bb4.z; o.w = acc[ii][3] + bb4.w;
    if (ACT == 1) { o.x = tanhf(o.x); o.y = tanhf(o.y); o.z = tanhf(o.z); o.w = tanhf(o.w); }
    long orow = mrow;
    if (CSWAP) orow = (long)(mrow & (NB - 1)) * NT + (mrow >> 5);
    *(float4*)(C + orow * (long)ldc + n) = o;
  }
}

// softmax over S=128 per (t,b) row, in place
__global__ __launch_bounds__(128) void softmax_s(float* __restrict__ sc) {
  const long row = blockIdx.x;
  float* p = sc + row * NS;
  const float x = p[threadIdx.x];
  float mx = x;
  for (int o = 32; o; o >>= 1) mx = fmaxf(mx, __shfl_xor(mx, o));
  __shared__ float r0[2], r1[2];
  const int w = threadIdx.x >> 6;
  if ((threadIdx.x & 63) == 0) r0[w] = mx;
  __syncthreads();
  mx = fmaxf(r0[0], r0[1]);
  const float e = expf(x - mx);
  float sum = e;
  for (int o = 32; o; o >>= 1) sum += __shfl_xor(sum, o);
  if ((threadIdx.x & 63) == 0) r1[w] = sum;
  __syncthreads();
  sum = r1[0] + r1[1];
  p[threadIdx.x] = e / sum;
}

// softmax over VE=8000 per (b,t) row of d_out, in place
__global__ __launch_bounds__(256) void softmax_v(float* __restrict__ out) {
  const long row = blockIdx.x;
  float* p = out + row * NVE;
  float v[32];
  float mx = -1e30f;
  #pragma unroll
  for (int it = 0; it < 32; ++it) {
    const int idx = (it << 8) + threadIdx.x;
    v[it] = (idx < NVE) ? p[idx] : -1e30f;
    mx = fmaxf(mx, v[it]);
  }
  for (int o = 32; o; o >>= 1) mx = fmaxf(mx, __shfl_xor(mx, o));
  __shared__ float red[4], red2[4];
  const int w = threadIdx.x >> 6;
  if ((threadIdx.x & 63) == 0) red[w] = mx;
  __syncthreads();
  mx = fmaxf(fmaxf(red[0], red[1]), fmaxf(red[2], red[3]));
  float sum = 0.0f;
  #pragma unroll
  for (int it = 0; it < 32; ++it) {
    const int idx = (it << 8) + threadIdx.x;
    if (idx < NVE) { v[it] = expf(v[it] - mx); sum += v[it]; }
  }
  for (int o = 32; o; o >>= 1) sum += __shfl_xor(sum, o);
  if ((threadIdx.x & 63) == 0) red2[w] = sum;
  __syncthreads();
  sum = red2[0] + red2[1] + red2[2] + red2[3];
  const float inv = 1.0f / sum;
  #pragma unroll
  for (int it = 0; it < 32; ++it) {
    const int idx = (it << 8) + threadIdx.x;
    if (idx < NVE) p[idx] = v[it] * inv;
  }
}

extern "C" void kernel_launch(void* const* d_in, const int* in_sizes, int n_in,
                              void* d_out, int out_size, void* d_ws, size_t ws_size,
                              hipStream_t stream) {
  const int*   in_tok = (const int*)d_in[0];
  const int*   out_tok = (const int*)d_in[1];
  const float* Wa    = (const float*)d_in[2];
  const float* ba    = (const float*)d_in[3];
  const float* W1    = (const float*)d_in[4];
  const float* b1    = (const float*)d_in[5];
  const float* W2    = (const float*)d_in[6];
  const float* b2    = (const float*)d_in[7];
  const float* We_ih = (const float*)d_in[8];
  const float* We_hh = (const float*)d_in[9];
  const float* be_ih = (const float*)d_in[10];
  const float* be_hh = (const float*)d_in[11];
  const float* Wd_ih = (const float*)d_in[12];
  const float* Wd_hh = (const float*)d_in[13];
  const float* bd_ih = (const float*)d_in[14];
  const float* bd_hh = (const float*)d_in[15];

  float* ws      = (float*)d_ws;
  float* h_buf   = ws;                 // 2*32*512
  float* enc_out = ws + 32768;         // 128*32*512
  float* dec_h   = ws + 2129920;       // 128*32*512
  float* proj    = ws + 4227072;       // 128*32*512
  float* scores  = ws + 6324224;       // 128*32*128
  float* ctx     = ws + 6848512;       // 128*32*512
  float* hid     = ws + 8945664;       // 128*32*512
  int*   flags   = (int*)(ws + 11042816);  // 256 ints
  float* out     = (float*)d_out;

  (void)hipMemsetAsync((void*)flags, 0, 256 * sizeof(int), stream);

  // 1. encoder + decoder-LSTM scan
  {
    void* args[14];
    args[0] = (void*)&in_tok; args[1] = (void*)&out_tok;
    args[2] = (void*)&We_ih;  args[3] = (void*)&We_hh;
    args[4] = (void*)&be_ih;  args[5] = (void*)&be_hh;
    args[6] = (void*)&Wd_ih;  args[7] = (void*)&Wd_hh;
    args[8] = (void*)&bd_ih;  args[9] = (void*)&bd_hh;
    args[10] = (void*)&h_buf; args[11] = (void*)&enc_out; args[12] = (void*)&dec_h;
    args[13] = (void*)&flags;
    (void)hipLaunchCooperativeKernel((void*)scan_kernel, dim3(256), dim3(256), args, 0, stream);
  }

  // 2. proj_enc = enc_out @ Wa^T + ba           [4096,512] K=512
  gemm128<0,0><<<dim3(8,32,1), 256, 0, stream>>>(
      enc_out, Wa, proj, ba, nullptr, 1 << 30,
      4096, 512, 512, 512, 512, 512);

  // 3. scores[t,b,s] = dec_h . proj_enc (batched over b)   M=T,N=S,K=H
  gemm64<0,0,0><<<dim3(2,2,NB), 256, 0, stream>>>(
      dec_h, proj, scores, nullptr, nullptr, 1 << 30,
      NT, NS, NH, NB * NH, NB * NH, NB * NS,
      (long)NH, (long)NH, (long)NS);

  // 4. softmax over s
  softmax_s<<<dim3(NT * NB), 128, 0, stream>>>(scores);

  // 5. context[t,b,h] = w @ enc_out (batched over b, B is [K][N])  M=T,N=H,K=S
  gemm64<1,0,0><<<dim3(8,2,NB), 256, 0, stream>>>(
      scores, enc_out, ctx, nullptr, nullptr, 1 << 30,
      NT, NH, NS, NB * NS, NB * NH, NB * NH,
      (long)NS, (long)NH, (long)NH);

  // 6. hid = tanh(concat(dec_h, ctx) @ W1^T + b1)   [4096,512] K=1024
  gemm128<0,1><<<dim3(8,32,1), 256, 0, stream>>>(
      dec_h, W1, hid, b1, ctx, 512,
      4096, 512, 1024, 512, 1024, 512);

  // 7. logits = hid @ W2^T + b2 -> d_out[b][t][v]   [4096,8000] K=512
  gemm128<1,0><<<dim3(125,32,1), 256, 0, stream>>>(
      hid, W2, out, b2, nullptr, 1 << 30,
      4096, NVE, 512, 512, 512, NVE);

  // 8. softmax over vocab, in place on d_out
  softmax_v<<<dim3(NB * NT), 256, 0, stream>>>(out);
}